// Round 9
// baseline (15940.833 us; speedup 1.0000x reference)
//
#include <hip/hip_runtime.h>
#include <stdint.h>

#define T_STEPS 2048
#define BATCH 32
#define EDIM 512
#define HDIM 512

typedef __attribute__((ext_vector_type(8))) short bf16x8;
typedef __attribute__((ext_vector_type(4))) float f32x4;
typedef unsigned long long u64t;

// ---- ws layout ----
//   0x000000 hbuf[2][32][512] u32 packed h      (128KB)
//   0x020000 done2[256] u32 per-wave flags (pad 4KB)
//   0x021000 c_ws[32][512] f32                  (64KB)
//   0x031000 Wh 2MB | 0x231000 Wl | 0x431000 Uh | 0x631000 Ul
//   0x831000 xWc[TCH][32][2048] f32             (TCH * 256KB)
#define FIXED_WS 0x831000ull

__device__ inline unsigned short f2bf(float x){
    unsigned u = __float_as_uint(x);
    unsigned r = (u + 0x7fffu + ((u >> 16) & 1u)) >> 16;
    return (unsigned short)r;
}
__device__ inline float bf2f(unsigned short s){
    return __uint_as_float(((unsigned)s) << 16);
}

// Shared prep: frag-pack W/U (hi/lo) + init hbuf parity0 with h0. (proven R7/R8)
__global__ void prep_kernel(const float* __restrict__ W, const float* __restrict__ U,
                            const float* __restrict__ h0,
                            unsigned short* __restrict__ Wh, unsigned short* __restrict__ Wl,
                            unsigned short* __restrict__ Uh, unsigned short* __restrict__ Ul,
                            unsigned* __restrict__ hbuf){
    int idx = blockIdx.x * blockDim.x + threadIdx.x;
    int stride = gridDim.x * blockDim.x;
    const int total = 2 * EDIM * 2048;
    for (int i = idx; i < total; i += stride){
        int mat = i >> 20;
        int r = i & 1048575;
        int k = r >> 11;
        int col = r & 2047;
        float v = (mat ? U : W)[(size_t)k * 2048 + col];
        unsigned short hi = f2bf(v);
        unsigned short lo = f2bf(v - bf2f(hi));
        int cg = (col & 511) >> 4;
        int hc = col & 15;
        int g  = col >> 9;
        int kb = k >> 5;
        int kgrp = (k >> 3) & 3;
        int j = k & 7;
        size_t dst = (size_t)cg * 32768 + (size_t)kb * 2048 + (size_t)g * 512
                   + (size_t)(kgrp * 16 + hc) * 8 + j;
        if (mat){ Uh[dst] = hi; Ul[dst] = lo; } else { Wh[dst] = hi; Wl[dst] = lo; }
    }
    for (int i = idx; i < BATCH * HDIM; i += stride){
        float v = h0[i];
        unsigned short hi = f2bf(v);
        unsigned short lo = f2bf(v - bf2f(hi));
        hbuf[i] = (unsigned)hi | ((unsigned)lo << 16);
    }
}

// xWc[tc] = src[:, t0+tc, :] @ W   (plain GEMM, full chip, 3-pass hi/lo)
__global__ __launch_bounds__(256) void xw_gemm_chunk(
        const float* __restrict__ src,
        const unsigned short* __restrict__ Wh, const unsigned short* __restrict__ Wl,
        float* __restrict__ xWc, int t0){
    const int bid = blockIdx.x;          // (TCH/4) * 32
    const int mtile = bid >> 5;
    const int cg = bid & 31;
    const int tid = threadIdx.x;
    const int lane = tid & 63;
    const int w = tid >> 6;
    const int tc = mtile * 4 + w;
    const int t = t0 + tc;
    const int lc = lane & 15;
    const int kgrp = lane >> 4;

    const uint4* WhF = reinterpret_cast<const uint4*>(Wh) + (size_t)cg * 4096;
    const uint4* WlF = reinterpret_cast<const uint4*>(Wl) + (size_t)cg * 4096;

    f32x4 acc[2][4];
    #pragma unroll
    for (int bt = 0; bt < 2; bt++)
        #pragma unroll
        for (int ct = 0; ct < 4; ct++)
            #pragma unroll
            for (int r = 0; r < 4; r++) acc[bt][ct][r] = 0.f;

    for (int kb = 0; kb < 16; kb++){
        bf16x8 ah[2], al[2];
        #pragma unroll
        for (int bt = 0; bt < 2; bt++){
            const float* xp = src + ((size_t)(bt * 16 + lc) * 2048 + t) * 512 + kb * 32 + kgrp * 8;
            float xv[8];
            *reinterpret_cast<float4*>(&xv[0]) = *reinterpret_cast<const float4*>(xp);
            *reinterpret_cast<float4*>(&xv[4]) = *reinterpret_cast<const float4*>(xp + 4);
            #pragma unroll
            for (int j = 0; j < 8; j++){
                unsigned short hi = f2bf(xv[j]);
                ah[bt][j] = (short)hi;
                al[bt][j] = (short)f2bf(xv[j] - bf2f(hi));
            }
        }
        #pragma unroll
        for (int ct = 0; ct < 4; ct++){
            uint4 bh4 = WhF[kb * 256 + ct * 64 + lane];
            uint4 bl4 = WlF[kb * 256 + ct * 64 + lane];
            bf16x8 bh = *reinterpret_cast<bf16x8*>(&bh4);
            bf16x8 bl = *reinterpret_cast<bf16x8*>(&bl4);
            #pragma unroll
            for (int bt = 0; bt < 2; bt++){
                acc[bt][ct] = __builtin_amdgcn_mfma_f32_16x16x32_bf16(ah[bt], bh, acc[bt][ct], 0, 0, 0);
                acc[bt][ct] = __builtin_amdgcn_mfma_f32_16x16x32_bf16(ah[bt], bl, acc[bt][ct], 0, 0, 0);
                acc[bt][ct] = __builtin_amdgcn_mfma_f32_16x16x32_bf16(al[bt], bh, acc[bt][ct], 0, 0, 0);
            }
        }
    }
    #pragma unroll
    for (int bt = 0; bt < 2; bt++)
        #pragma unroll
        for (int ct = 0; ct < 4; ct++)
            #pragma unroll
            for (int r = 0; r < 4; r++){
                int row_b = bt * 16 + kgrp * 4 + r;
                xWc[((size_t)tc * 32 + row_b) * 2048 + ct * 512 + cg * 16 + lc] = acc[bt][ct][r];
            }
}

// Scan: empty loop body + contention-free per-wave flag release, tight poll.
__global__ __launch_bounds__(512, 1) void lstm_scan_fast(
        const float* __restrict__ bias, const float* __restrict__ c0,
        const unsigned short* __restrict__ Uh, const unsigned short* __restrict__ Ul,
        unsigned* __restrict__ hbuf, unsigned* __restrict__ done2,
        const float* __restrict__ xWc, float* __restrict__ c_ws,
        float* __restrict__ out, int t0, int tlen){
    const int tid  = threadIdx.x;
    const int cg   = blockIdx.x;        // 0..31
    const int lane = tid & 63;
    const int w    = tid >> 6;
    const int bt   = w >> 2;
    const int kq   = w & 3;
    const int lc   = lane & 15;
    const int kgrp = lane >> 4;
    const int row  = bt * 16 + lc;

    __shared__ float z_lds[4][BATCH][65];

    const int cb  = tid >> 4;
    const int chc = tid & 15;
    const int col = cg * 16 + chc;
    float c_state = (t0 == 0) ? c0[(size_t)cb * HDIM + col] : c_ws[(size_t)cb * HDIM + col];
    float bias_g[4];
    #pragma unroll
    for (int g = 0; g < 4; g++) bias_g[g] = bias[g * HDIM + col];

    // U fragments -> registers (128 VGPR)
    const uint4* UhF = reinterpret_cast<const uint4*>(Uh) + (size_t)cg * 4096;
    const uint4* UlF = reinterpret_cast<const uint4*>(Ul) + (size_t)cg * 4096;
    bf16x8 ufh[4][4], ufl[4][4];
    #pragma unroll
    for (int i = 0; i < 4; i++){
        int kb = kq * 4 + i;
        #pragma unroll
        for (int ct = 0; ct < 4; ct++){
            uint4 a  = UhF[kb * 256 + ct * 64 + lane];
            uint4 b2 = UlF[kb * 256 + ct * 64 + lane];
            ufh[i][ct] = *reinterpret_cast<bf16x8*>(&a);
            ufl[i][ct] = *reinterpret_cast<bf16x8*>(&b2);
        }
    }

    f32x4 acc[4];
    #pragma unroll
    for (int ct = 0; ct < 4; ct++)
        #pragma unroll
        for (int r = 0; r < 4; r++) acc[ct][r] = 0.f;

    for (int t = t0; t < t0 + tlen; t++){
        // xW partials issued before the poll so HBM/L3 latency hides under it
        const float* xwp = xWc + ((size_t)(t - t0) * 32 + cb) * 2048 + col;
        float zx0 = xwp[0], zx1 = xwp[512], zx2 = xwp[1024], zx3 = xwp[1536];

        // ---- wait for h_t: all 256 per-wave flags >= t (wave 0 polls) ----
        if (t > 0){
            if (w == 0){
                const u64t* dp = reinterpret_cast<const u64t*>(done2);
                const unsigned tgt = (unsigned)t;
                while (true){
                    u64t a = __hip_atomic_load(dp + lane * 2,     __ATOMIC_RELAXED, __HIP_MEMORY_SCOPE_AGENT);
                    u64t b = __hip_atomic_load(dp + lane * 2 + 1, __ATOMIC_RELAXED, __HIP_MEMORY_SCOPE_AGENT);
                    bool ok = ((unsigned)a >= tgt) && ((unsigned)(a >> 32) >= tgt)
                           && ((unsigned)b >= tgt) && ((unsigned)(b >> 32) >= tgt);
                    if (__all(ok)) break;
                }
            }
            __syncthreads();
        }

        // ---- payload: 16 dense u64 agent loads -> A fragments ----
        const u64t* hp = reinterpret_cast<const u64t*>(hbuf)
                       + (size_t)(t & 1) * 8192 + (size_t)row * 256;
        u64t hv[16];
        #pragma unroll
        for (int i = 0; i < 4; i++){
            int base = (kq * 4 + i) * 16 + kgrp * 4;
            #pragma unroll
            for (int jp = 0; jp < 4; jp++)
                hv[i * 4 + jp] = __hip_atomic_load(hp + base + jp,
                                                   __ATOMIC_RELAXED, __HIP_MEMORY_SCOPE_AGENT);
        }

        // ---- h_t @ U (3-pass hi/lo), U from registers ----
        #pragma unroll
        for (int i = 0; i < 4; i++){
            bf16x8 ah, al;
            #pragma unroll
            for (int jp = 0; jp < 4; jp++){
                u64t q = hv[i * 4 + jp];
                unsigned a = (unsigned)q;
                unsigned b = (unsigned)(q >> 32);
                ah[jp * 2    ] = (short)(a & 0xffffu); al[jp * 2    ] = (short)(a >> 16);
                ah[jp * 2 + 1] = (short)(b & 0xffffu); al[jp * 2 + 1] = (short)(b >> 16);
            }
            #pragma unroll
            for (int ct = 0; ct < 4; ct++){
                acc[ct] = __builtin_amdgcn_mfma_f32_16x16x32_bf16(ah, ufh[i][ct], acc[ct], 0, 0, 0);
                acc[ct] = __builtin_amdgcn_mfma_f32_16x16x32_bf16(ah, ufl[i][ct], acc[ct], 0, 0, 0);
                acc[ct] = __builtin_amdgcn_mfma_f32_16x16x32_bf16(al, ufh[i][ct], acc[ct], 0, 0, 0);
            }
        }

        // ---- exchange partial z through LDS ----
        #pragma unroll
        for (int ct = 0; ct < 4; ct++)
            #pragma unroll
            for (int r = 0; r < 4; r++)
                z_lds[kq][bt * 16 + kgrp * 4 + r][ct * 16 + lc] = acc[ct][r];
        __syncthreads();

        // ---- gates + per-wave release ----
        {
            float z0 = z_lds[0][cb][chc]      + z_lds[1][cb][chc]      + z_lds[2][cb][chc]      + z_lds[3][cb][chc]      + zx0 + bias_g[0];
            float z1 = z_lds[0][cb][16 + chc] + z_lds[1][cb][16 + chc] + z_lds[2][cb][16 + chc] + z_lds[3][cb][16 + chc] + zx1 + bias_g[1];
            float z2 = z_lds[0][cb][32 + chc] + z_lds[1][cb][32 + chc] + z_lds[2][cb][32 + chc] + z_lds[3][cb][32 + chc] + zx2 + bias_g[2];
            float z3 = z_lds[0][cb][48 + chc] + z_lds[1][cb][48 + chc] + z_lds[2][cb][48 + chc] + z_lds[3][cb][48 + chc] + zx3 + bias_g[3];
            float ig = 1.f / (1.f + __expf(-z0));
            float fg = 1.f / (1.f + __expf(-z1));
            float gg = tanhf(z2);
            float og = 1.f / (1.f + __expf(-z3));
            float cn = fg * c_state + ig * gg;
            c_state = cn;
            float hn = og * tanhf(cn);
            out[16384 + ((size_t)t * BATCH + cb) * HDIM + col] = hn;
            if (t == T_STEPS - 1){
                out[(size_t)cb * HDIM + col] = hn;
                out[16384 + (size_t)T_STEPS * BATCH * HDIM + (size_t)cb * HDIM + col] = hn;
            }
            unsigned short hi = f2bf(hn);
            unsigned short lo = f2bf(hn - bf2f(hi));
            __hip_atomic_store(&hbuf[(size_t)((t + 1) & 1) * (BATCH * HDIM) + (size_t)cb * HDIM + col],
                               (unsigned)hi | ((unsigned)lo << 16),
                               __ATOMIC_RELAXED, __HIP_MEMORY_SCOPE_AGENT);
        }
        // wave-local drain of this wave's stores, then fire this wave's flag
        asm volatile("s_waitcnt vmcnt(0)" ::: "memory");
        if (lane == 0)
            __hip_atomic_store(&done2[cg * 8 + w], (unsigned)(t + 1),
                               __ATOMIC_RELAXED, __HIP_MEMORY_SCOPE_AGENT);

        #pragma unroll
        for (int ct = 0; ct < 4; ct++)
            #pragma unroll
            for (int r = 0; r < 4; r++) acc[ct][r] = 0.f;
    }
    c_ws[(size_t)cb * HDIM + col] = c_state;
}

// ============================ FALLBACK: R7 scan (proven) ====================
__global__ __launch_bounds__(512, 2) void lstm_scan_r7(
        const float* __restrict__ src, const float* __restrict__ bias,
        const float* __restrict__ c0,
        const unsigned short* __restrict__ Wh, const unsigned short* __restrict__ Wl,
        const unsigned short* __restrict__ Uh, const unsigned short* __restrict__ Ul,
        unsigned* __restrict__ hbuf, unsigned* __restrict__ cnt,
        float* __restrict__ out){
    const int tid  = threadIdx.x;
    const int cg   = blockIdx.x;
    const int lane = tid & 63;
    const int w    = tid >> 6;
    const int bt   = w >> 2;
    const int kq   = w & 3;
    const int lc   = lane & 15;
    const int kgrp = lane >> 4;
    const int row  = bt * 16 + lc;

    __shared__ float z_lds[4][BATCH][65];

    const int cb  = tid >> 4;
    const int chc = tid & 15;
    const int col = cg * 16 + chc;
    float c_state = c0[(size_t)cb * HDIM + col];
    float bias_g[4];
    #pragma unroll
    for (int g = 0; g < 4; g++) bias_g[g] = bias[g * HDIM + col];

    const uint4* WhF = reinterpret_cast<const uint4*>(Wh) + (size_t)cg * 4096;
    const uint4* WlF = reinterpret_cast<const uint4*>(Wl) + (size_t)cg * 4096;
    const uint4* UhF = reinterpret_cast<const uint4*>(Uh) + (size_t)cg * 4096;
    const uint4* UlF = reinterpret_cast<const uint4*>(Ul) + (size_t)cg * 4096;

    f32x4 acc[4];
    #pragma unroll
    for (int ct = 0; ct < 4; ct++)
        #pragma unroll
        for (int r = 0; r < 4; r++) acc[ct][r] = 0.f;

    auto phaseA = [&](int t){
        #pragma unroll
        for (int i = 0; i < 4; i++){
            int kb = kq * 4 + i;
            const float* xp = src + ((size_t)row * T_STEPS + t) * EDIM + kb * 32 + kgrp * 8;
            float xv[8];
            *reinterpret_cast<float4*>(&xv[0]) = *reinterpret_cast<const float4*>(xp);
            *reinterpret_cast<float4*>(&xv[4]) = *reinterpret_cast<const float4*>(xp + 4);
            bf16x8 ah, al;
            #pragma unroll
            for (int j = 0; j < 8; j++){
                unsigned short hi = f2bf(xv[j]);
                ah[j] = (short)hi;
                al[j] = (short)f2bf(xv[j] - bf2f(hi));
            }
            #pragma unroll
            for (int ct = 0; ct < 4; ct++){
                uint4 bh4 = WhF[kb * 256 + ct * 64 + lane];
                uint4 bl4 = WlF[kb * 256 + ct * 64 + lane];
                bf16x8 bh = *reinterpret_cast<bf16x8*>(&bh4);
                bf16x8 bl = *reinterpret_cast<bf16x8*>(&bl4);
                acc[ct] = __builtin_amdgcn_mfma_f32_16x16x32_bf16(ah, bh, acc[ct], 0, 0, 0);
                acc[ct] = __builtin_amdgcn_mfma_f32_16x16x32_bf16(ah, bl, acc[ct], 0, 0, 0);
                acc[ct] = __builtin_amdgcn_mfma_f32_16x16x32_bf16(al, bh, acc[ct], 0, 0, 0);
            }
        }
    };

    phaseA(0);

    for (int t = 0; t < T_STEPS; t++){
        if (t > 0){
            if (w == 0){
                const unsigned need = 32u * (unsigned)((t + 1) >> 1);
                while (__hip_atomic_load(&cnt[t & 1], __ATOMIC_RELAXED, __HIP_MEMORY_SCOPE_AGENT) < need)
                    __builtin_amdgcn_s_sleep(1);
            }
            __syncthreads();
        }

        const u64t* hp = reinterpret_cast<const u64t*>(hbuf)
                       + (size_t)(t & 1) * 8192 + (size_t)row * 256;
        u64t hv[16];
        #pragma unroll
        for (int i = 0; i < 4; i++){
            int base = (kq * 4 + i) * 16 + kgrp * 4;
            #pragma unroll
            for (int jp = 0; jp < 4; jp++)
                hv[i * 4 + jp] = __hip_atomic_load(hp + base + jp,
                                                   __ATOMIC_RELAXED, __HIP_MEMORY_SCOPE_AGENT);
        }

        #pragma unroll
        for (int i = 0; i < 4; i++){
            int kb = kq * 4 + i;
            bf16x8 ah, al;
            #pragma unroll
            for (int jp = 0; jp < 4; jp++){
                u64t q = hv[i * 4 + jp];
                unsigned a = (unsigned)q;
                unsigned b = (unsigned)(q >> 32);
                ah[jp * 2    ] = (short)(a & 0xffffu); al[jp * 2    ] = (short)(a >> 16);
                ah[jp * 2 + 1] = (short)(b & 0xffffu); al[jp * 2 + 1] = (short)(b >> 16);
            }
            #pragma unroll
            for (int ct = 0; ct < 4; ct++){
                uint4 uh4 = UhF[kb * 256 + ct * 64 + lane];
                uint4 ul4 = UlF[kb * 256 + ct * 64 + lane];
                bf16x8 uh = *reinterpret_cast<bf16x8*>(&uh4);
                bf16x8 ul = *reinterpret_cast<bf16x8*>(&ul4);
                acc[ct] = __builtin_amdgcn_mfma_f32_16x16x32_bf16(ah, uh, acc[ct], 0, 0, 0);
                acc[ct] = __builtin_amdgcn_mfma_f32_16x16x32_bf16(ah, ul, acc[ct], 0, 0, 0);
                acc[ct] = __builtin_amdgcn_mfma_f32_16x16x32_bf16(al, uh, acc[ct], 0, 0, 0);
            }
        }

        #pragma unroll
        for (int ct = 0; ct < 4; ct++)
            #pragma unroll
            for (int r = 0; r < 4; r++)
                z_lds[kq][bt * 16 + kgrp * 4 + r][ct * 16 + lc] = acc[ct][r];
        __syncthreads();

        {
            float z[4];
            #pragma unroll
            for (int g = 0; g < 4; g++)
                z[g] = z_lds[0][cb][g * 16 + chc] + z_lds[1][cb][g * 16 + chc]
                     + z_lds[2][cb][g * 16 + chc] + z_lds[3][cb][g * 16 + chc] + bias_g[g];
            float ig = 1.f / (1.f + __expf(-z[0]));
            float fg = 1.f / (1.f + __expf(-z[1]));
            float gg = tanhf(z[2]);
            float og = 1.f / (1.f + __expf(-z[3]));
            float cn = fg * c_state + ig * gg;
            c_state = cn;
            float hn = og * tanhf(cn);
            out[16384 + ((size_t)t * BATCH + cb) * HDIM + col] = hn;
            if (t == T_STEPS - 1){
                out[(size_t)cb * HDIM + col] = hn;
                out[16384 + (size_t)T_STEPS * BATCH * HDIM + (size_t)cb * HDIM + col] = hn;
            }
            unsigned short hi = f2bf(hn);
            unsigned short lo = f2bf(hn - bf2f(hi));
            __hip_atomic_store(&hbuf[(size_t)((t + 1) & 1) * (BATCH * HDIM) + (size_t)cb * HDIM + col],
                               (unsigned)hi | ((unsigned)lo << 16),
                               __ATOMIC_RELAXED, __HIP_MEMORY_SCOPE_AGENT);
        }
        __syncthreads();
        if (tid == 0)
            __hip_atomic_fetch_add(&cnt[(t + 1) & 1], 1u,
                                   __ATOMIC_RELAXED, __HIP_MEMORY_SCOPE_AGENT);

        #pragma unroll
        for (int ct = 0; ct < 4; ct++)
            #pragma unroll
            for (int r = 0; r < 4; r++) acc[ct][r] = 0.f;
        if (t + 1 < T_STEPS) phaseA(t + 1);
    }
}

// ============================ LAUNCH =======================================
extern "C" void kernel_launch(void* const* d_in, const int* in_sizes, int n_in,
                              void* d_out, int out_size, void* d_ws, size_t ws_size,
                              hipStream_t stream){
    const float* src = (const float*)d_in[0];
    const float* W   = (const float*)d_in[1];
    const float* U   = (const float*)d_in[2];
    const float* b   = (const float*)d_in[3];
    const float* h0  = (const float*)d_in[4];
    const float* c0  = (const float*)d_in[5];
    float* out = (float*)d_out;
    char* ws = (char*)d_ws;

    int TCH = 0;
    const int cand[5] = {256, 128, 64, 32, 16};
    for (int i = 0; i < 5; i++){
        if (FIXED_WS + (size_t)cand[i] * 262144ull <= ws_size){ TCH = cand[i]; break; }
    }

    if (TCH > 0){
        unsigned*       hbuf = (unsigned*)(ws);
        unsigned*       done2= (unsigned*)(ws + 0x020000ull);
        float*          c_ws = (float*)(ws + 0x021000ull);
        unsigned short* Wh   = (unsigned short*)(ws + 0x031000ull);
        unsigned short* Wl   = (unsigned short*)(ws + 0x231000ull);
        unsigned short* Uh   = (unsigned short*)(ws + 0x431000ull);
        unsigned short* Ul   = (unsigned short*)(ws + 0x631000ull);
        float*          xWc  = (float*)(ws + FIXED_WS);

        hipMemsetAsync(done2, 0, 1024, stream);
        prep_kernel<<<1024, 256, 0, stream>>>(W, U, h0, Wh, Wl, Uh, Ul, hbuf);
        const int nch = T_STEPS / TCH;
        for (int i = 0; i < nch; i++){
            int t0 = i * TCH;
            xw_gemm_chunk<<<(TCH / 4) * 32, 256, 0, stream>>>(src, Wh, Wl, xWc, t0);
            lstm_scan_fast<<<32, 512, 0, stream>>>(b, c0, Uh, Ul, hbuf, done2,
                                                   xWc, c_ws, out, t0, TCH);
        }
    } else {
        unsigned*       hbuf = (unsigned*)(ws);
        unsigned*       cnt  = (unsigned*)(ws + 0x20000);
        unsigned short* Wh   = (unsigned short*)(ws + 0x21000);
        unsigned short* Wl   = Wh + 1048576;
        unsigned short* Uh   = Wl + 1048576;
        unsigned short* Ul   = Uh + 1048576;
        hipMemsetAsync(cnt, 0, 8, stream);
        prep_kernel<<<1024, 256, 0, stream>>>(W, U, h0, Wh, Wl, Uh, Ul, hbuf);
        lstm_scan_r7<<<32, 512, 0, stream>>>(src, b, c0, Wh, Wl, Uh, Ul, hbuf, cnt, out);
    }
}

// Round 10
// 11693.981 us; speedup vs baseline: 1.3632x; 1.3632x over previous
//
#include <hip/hip_runtime.h>
#include <stdint.h>

#define T_STEPS 2048
#define BATCH 32
#define EDIM 512
#define HDIM 512

typedef __attribute__((ext_vector_type(8))) short bf16x8;
typedef __attribute__((ext_vector_type(4))) float f32x4;
typedef unsigned long long u64t;

// ---- ws layout ----
//   0x000000 hbuf[2][32][512] u32 packed h      (128KB)
//   0x020000 done[32] u32 per-WG flags (pad 4KB)
//   0x021000 c_ws[32][512] f32                  (64KB)
//   0x031000 Wh 2MB | 0x231000 Wl | 0x431000 Uh | 0x631000 Ul
//   0x831000 xWc[TCH][32][2048] f32             (TCH * 256KB)
#define FIXED_WS 0x831000ull

__device__ inline unsigned short f2bf(float x){
    unsigned u = __float_as_uint(x);
    unsigned r = (u + 0x7fffu + ((u >> 16) & 1u)) >> 16;
    return (unsigned short)r;
}
__device__ inline float bf2f(unsigned short s){
    return __uint_as_float(((unsigned)s) << 16);
}
__device__ inline float sigmoid_f(float x){
    return __builtin_amdgcn_rcpf(1.f + __expf(-x));
}
__device__ inline float tanh_f(float x){
    float xc = fminf(30.f, fmaxf(-30.f, x));
    float e = __expf(2.f * xc);
    return (e - 1.f) * __builtin_amdgcn_rcpf(e + 1.f);
}

// Shared prep: frag-pack W/U (hi/lo) + init hbuf parity0 with h0. (proven)
__global__ void prep_kernel(const float* __restrict__ W, const float* __restrict__ U,
                            const float* __restrict__ h0,
                            unsigned short* __restrict__ Wh, unsigned short* __restrict__ Wl,
                            unsigned short* __restrict__ Uh, unsigned short* __restrict__ Ul,
                            unsigned* __restrict__ hbuf){
    int idx = blockIdx.x * blockDim.x + threadIdx.x;
    int stride = gridDim.x * blockDim.x;
    const int total = 2 * EDIM * 2048;
    for (int i = idx; i < total; i += stride){
        int mat = i >> 20;
        int r = i & 1048575;
        int k = r >> 11;
        int col = r & 2047;
        float v = (mat ? U : W)[(size_t)k * 2048 + col];
        unsigned short hi = f2bf(v);
        unsigned short lo = f2bf(v - bf2f(hi));
        int cg = (col & 511) >> 4;
        int hc = col & 15;
        int g  = col >> 9;
        int kb = k >> 5;
        int kgrp = (k >> 3) & 3;
        int j = k & 7;
        size_t dst = (size_t)cg * 32768 + (size_t)kb * 2048 + (size_t)g * 512
                   + (size_t)(kgrp * 16 + hc) * 8 + j;
        if (mat){ Uh[dst] = hi; Ul[dst] = lo; } else { Wh[dst] = hi; Wl[dst] = lo; }
    }
    for (int i = idx; i < BATCH * HDIM; i += stride){
        float v = h0[i];
        unsigned short hi = f2bf(v);
        unsigned short lo = f2bf(v - bf2f(hi));
        hbuf[i] = (unsigned)hi | ((unsigned)lo << 16);
    }
}

// xWc[tc] = src[:, t0+tc, :] @ W   (plain GEMM, full chip, 3-pass hi/lo)
__global__ __launch_bounds__(256) void xw_gemm_chunk(
        const float* __restrict__ src,
        const unsigned short* __restrict__ Wh, const unsigned short* __restrict__ Wl,
        float* __restrict__ xWc, int t0){
    const int bid = blockIdx.x;          // (TCH/4) * 32
    const int mtile = bid >> 5;
    const int cg = bid & 31;
    const int tid = threadIdx.x;
    const int lane = tid & 63;
    const int w = tid >> 6;
    const int tc = mtile * 4 + w;
    const int t = t0 + tc;
    const int lc = lane & 15;
    const int kgrp = lane >> 4;

    const uint4* WhF = reinterpret_cast<const uint4*>(Wh) + (size_t)cg * 4096;
    const uint4* WlF = reinterpret_cast<const uint4*>(Wl) + (size_t)cg * 4096;

    f32x4 acc[2][4];
    #pragma unroll
    for (int bt = 0; bt < 2; bt++)
        #pragma unroll
        for (int ct = 0; ct < 4; ct++)
            #pragma unroll
            for (int r = 0; r < 4; r++) acc[bt][ct][r] = 0.f;

    for (int kb = 0; kb < 16; kb++){
        bf16x8 ah[2], al[2];
        #pragma unroll
        for (int bt = 0; bt < 2; bt++){
            const float* xp = src + ((size_t)(bt * 16 + lc) * 2048 + t) * 512 + kb * 32 + kgrp * 8;
            float xv[8];
            *reinterpret_cast<float4*>(&xv[0]) = *reinterpret_cast<const float4*>(xp);
            *reinterpret_cast<float4*>(&xv[4]) = *reinterpret_cast<const float4*>(xp + 4);
            #pragma unroll
            for (int j = 0; j < 8; j++){
                unsigned short hi = f2bf(xv[j]);
                ah[bt][j] = (short)hi;
                al[bt][j] = (short)f2bf(xv[j] - bf2f(hi));
            }
        }
        #pragma unroll
        for (int ct = 0; ct < 4; ct++){
            uint4 bh4 = WhF[kb * 256 + ct * 64 + lane];
            uint4 bl4 = WlF[kb * 256 + ct * 64 + lane];
            bf16x8 bh = *reinterpret_cast<bf16x8*>(&bh4);
            bf16x8 bl = *reinterpret_cast<bf16x8*>(&bl4);
            #pragma unroll
            for (int bt = 0; bt < 2; bt++){
                acc[bt][ct] = __builtin_amdgcn_mfma_f32_16x16x32_bf16(ah[bt], bh, acc[bt][ct], 0, 0, 0);
                acc[bt][ct] = __builtin_amdgcn_mfma_f32_16x16x32_bf16(ah[bt], bl, acc[bt][ct], 0, 0, 0);
                acc[bt][ct] = __builtin_amdgcn_mfma_f32_16x16x32_bf16(al[bt], bh, acc[bt][ct], 0, 0, 0);
            }
        }
    }
    #pragma unroll
    for (int bt = 0; bt < 2; bt++)
        #pragma unroll
        for (int ct = 0; ct < 4; ct++)
            #pragma unroll
            for (int r = 0; r < 4; r++){
                int row_b = bt * 16 + kgrp * 4 + r;
                xWc[((size_t)tc * 32 + row_b) * 2048 + ct * 512 + cg * 16 + lc] = acc[bt][ct][r];
            }
}

// Scan: per-WG store release (no RMW), 2-line sleep-backed all-wave poll,
// out[] store after the flag, fast transcendentals.
__global__ __launch_bounds__(512, 1) void lstm_scan_fast(
        const float* __restrict__ bias, const float* __restrict__ c0,
        const unsigned short* __restrict__ Uh, const unsigned short* __restrict__ Ul,
        unsigned* __restrict__ hbuf, unsigned* __restrict__ done,
        const float* __restrict__ xWc, float* __restrict__ c_ws,
        float* __restrict__ out, int t0, int tlen){
    const int tid  = threadIdx.x;
    const int cg   = blockIdx.x;        // 0..31
    const int lane = tid & 63;
    const int w    = tid >> 6;
    const int bt   = w >> 2;
    const int kq   = w & 3;
    const int lc   = lane & 15;
    const int kgrp = lane >> 4;
    const int row  = bt * 16 + lc;

    __shared__ float z_lds[4][BATCH][65];

    const int cb  = tid >> 4;
    const int chc = tid & 15;
    const int col = cg * 16 + chc;
    float c_state = (t0 == 0) ? c0[(size_t)cb * HDIM + col] : c_ws[(size_t)cb * HDIM + col];
    float bias_g[4];
    #pragma unroll
    for (int g = 0; g < 4; g++) bias_g[g] = bias[g * HDIM + col];

    // U fragments -> registers (128 VGPR)
    const uint4* UhF = reinterpret_cast<const uint4*>(Uh) + (size_t)cg * 4096;
    const uint4* UlF = reinterpret_cast<const uint4*>(Ul) + (size_t)cg * 4096;
    bf16x8 ufh[4][4], ufl[4][4];
    #pragma unroll
    for (int i = 0; i < 4; i++){
        int kb = kq * 4 + i;
        #pragma unroll
        for (int ct = 0; ct < 4; ct++){
            uint4 a  = UhF[kb * 256 + ct * 64 + lane];
            uint4 b2 = UlF[kb * 256 + ct * 64 + lane];
            ufh[i][ct] = *reinterpret_cast<bf16x8*>(&a);
            ufl[i][ct] = *reinterpret_cast<bf16x8*>(&b2);
        }
    }

    f32x4 acc[4];
    #pragma unroll
    for (int ct = 0; ct < 4; ct++)
        #pragma unroll
        for (int r = 0; r < 4; r++) acc[ct][r] = 0.f;

    for (int t = t0; t < t0 + tlen; t++){
        // xW partials issued before the poll so L3/HBM latency hides under it
        const float* xwp = xWc + ((size_t)(t - t0) * 32 + cb) * 2048 + col;
        float zx0 = xwp[0], zx1 = xwp[512], zx2 = xwp[1024], zx3 = xwp[1536];

        // ---- wait for h_t: every wave polls the 32 per-WG flags (2 lines) ----
        if (t > 0){
            const unsigned tgt = (unsigned)t;
            while (true){
                unsigned f = __hip_atomic_load(&done[lane & 31],
                                               __ATOMIC_RELAXED, __HIP_MEMORY_SCOPE_AGENT);
                if (__all(f >= tgt)) break;
                __builtin_amdgcn_s_sleep(1);
            }
        }

        // ---- payload: 16 dense u64 agent loads -> A fragments ----
        const u64t* hp = reinterpret_cast<const u64t*>(hbuf)
                       + (size_t)(t & 1) * 8192 + (size_t)row * 256;
        u64t hv[16];
        #pragma unroll
        for (int i = 0; i < 4; i++){
            int base = (kq * 4 + i) * 16 + kgrp * 4;
            #pragma unroll
            for (int jp = 0; jp < 4; jp++)
                hv[i * 4 + jp] = __hip_atomic_load(hp + base + jp,
                                                   __ATOMIC_RELAXED, __HIP_MEMORY_SCOPE_AGENT);
        }

        // ---- h_t @ U (3-pass hi/lo), U from registers ----
        #pragma unroll
        for (int i = 0; i < 4; i++){
            bf16x8 ah, al;
            #pragma unroll
            for (int jp = 0; jp < 4; jp++){
                u64t q = hv[i * 4 + jp];
                unsigned a = (unsigned)q;
                unsigned b = (unsigned)(q >> 32);
                ah[jp * 2    ] = (short)(a & 0xffffu); al[jp * 2    ] = (short)(a >> 16);
                ah[jp * 2 + 1] = (short)(b & 0xffffu); al[jp * 2 + 1] = (short)(b >> 16);
            }
            #pragma unroll
            for (int ct = 0; ct < 4; ct++){
                acc[ct] = __builtin_amdgcn_mfma_f32_16x16x32_bf16(ah, ufh[i][ct], acc[ct], 0, 0, 0);
                acc[ct] = __builtin_amdgcn_mfma_f32_16x16x32_bf16(ah, ufl[i][ct], acc[ct], 0, 0, 0);
                acc[ct] = __builtin_amdgcn_mfma_f32_16x16x32_bf16(al, ufh[i][ct], acc[ct], 0, 0, 0);
            }
        }

        // ---- exchange partial z through LDS ----
        #pragma unroll
        for (int ct = 0; ct < 4; ct++)
            #pragma unroll
            for (int r = 0; r < 4; r++)
                z_lds[kq][bt * 16 + kgrp * 4 + r][ct * 16 + lc] = acc[ct][r];
        __syncthreads();   // B1

        // ---- gates -> hbuf store -> release -> out store ----
        float hn;
        {
            float z0 = z_lds[0][cb][chc]      + z_lds[1][cb][chc]      + z_lds[2][cb][chc]      + z_lds[3][cb][chc]      + zx0 + bias_g[0];
            float z1 = z_lds[0][cb][16 + chc] + z_lds[1][cb][16 + chc] + z_lds[2][cb][16 + chc] + z_lds[3][cb][16 + chc] + zx1 + bias_g[1];
            float z2 = z_lds[0][cb][32 + chc] + z_lds[1][cb][32 + chc] + z_lds[2][cb][32 + chc] + z_lds[3][cb][32 + chc] + zx2 + bias_g[2];
            float z3 = z_lds[0][cb][48 + chc] + z_lds[1][cb][48 + chc] + z_lds[2][cb][48 + chc] + z_lds[3][cb][48 + chc] + zx3 + bias_g[3];
            float ig = sigmoid_f(z0);
            float fg = sigmoid_f(z1);
            float gg = tanh_f(z2);
            float og = sigmoid_f(z3);
            float cn = fg * c_state + ig * gg;
            c_state = cn;
            hn = og * tanh_f(cn);
            unsigned short hi = f2bf(hn);
            unsigned short lo = f2bf(hn - bf2f(hi));
            __hip_atomic_store(&hbuf[(size_t)((t + 1) & 1) * (BATCH * HDIM) + (size_t)cb * HDIM + col],
                               (unsigned)hi | ((unsigned)lo << 16),
                               __ATOMIC_RELAXED, __HIP_MEMORY_SCOPE_AGENT);
        }
        __syncthreads();   // B2: drains all waves' hbuf stores (vmcnt 0)
        if (tid == 0)
            __hip_atomic_store(&done[cg], (unsigned)(t + 1),
                               __ATOMIC_RELAXED, __HIP_MEMORY_SCOPE_AGENT);

        // hs store is NOT on the inter-WG critical path — after the flag
        out[16384 + ((size_t)t * BATCH + cb) * HDIM + col] = hn;
        if (t == T_STEPS - 1){
            out[(size_t)cb * HDIM + col] = hn;
            out[16384 + (size_t)T_STEPS * BATCH * HDIM + (size_t)cb * HDIM + col] = hn;
        }

        #pragma unroll
        for (int ct = 0; ct < 4; ct++)
            #pragma unroll
            for (int r = 0; r < 4; r++) acc[ct][r] = 0.f;
    }
    c_ws[(size_t)cb * HDIM + col] = c_state;
}

// ============================ FALLBACK: R7 scan (proven) ====================
__global__ __launch_bounds__(512, 2) void lstm_scan_r7(
        const float* __restrict__ src, const float* __restrict__ bias,
        const float* __restrict__ c0,
        const unsigned short* __restrict__ Wh, const unsigned short* __restrict__ Wl,
        const unsigned short* __restrict__ Uh, const unsigned short* __restrict__ Ul,
        unsigned* __restrict__ hbuf, unsigned* __restrict__ cnt,
        float* __restrict__ out){
    const int tid  = threadIdx.x;
    const int cg   = blockIdx.x;
    const int lane = tid & 63;
    const int w    = tid >> 6;
    const int bt   = w >> 2;
    const int kq   = w & 3;
    const int lc   = lane & 15;
    const int kgrp = lane >> 4;
    const int row  = bt * 16 + lc;

    __shared__ float z_lds[4][BATCH][65];

    const int cb  = tid >> 4;
    const int chc = tid & 15;
    const int col = cg * 16 + chc;
    float c_state = c0[(size_t)cb * HDIM + col];
    float bias_g[4];
    #pragma unroll
    for (int g = 0; g < 4; g++) bias_g[g] = bias[g * HDIM + col];

    const uint4* WhF = reinterpret_cast<const uint4*>(Wh) + (size_t)cg * 4096;
    const uint4* WlF = reinterpret_cast<const uint4*>(Wl) + (size_t)cg * 4096;
    const uint4* UhF = reinterpret_cast<const uint4*>(Uh) + (size_t)cg * 4096;
    const uint4* UlF = reinterpret_cast<const uint4*>(Ul) + (size_t)cg * 4096;

    f32x4 acc[4];
    #pragma unroll
    for (int ct = 0; ct < 4; ct++)
        #pragma unroll
        for (int r = 0; r < 4; r++) acc[ct][r] = 0.f;

    auto phaseA = [&](int t){
        #pragma unroll
        for (int i = 0; i < 4; i++){
            int kb = kq * 4 + i;
            const float* xp = src + ((size_t)row * T_STEPS + t) * EDIM + kb * 32 + kgrp * 8;
            float xv[8];
            *reinterpret_cast<float4*>(&xv[0]) = *reinterpret_cast<const float4*>(xp);
            *reinterpret_cast<float4*>(&xv[4]) = *reinterpret_cast<const float4*>(xp + 4);
            bf16x8 ah, al;
            #pragma unroll
            for (int j = 0; j < 8; j++){
                unsigned short hi = f2bf(xv[j]);
                ah[j] = (short)hi;
                al[j] = (short)f2bf(xv[j] - bf2f(hi));
            }
            #pragma unroll
            for (int ct = 0; ct < 4; ct++){
                uint4 bh4 = WhF[kb * 256 + ct * 64 + lane];
                uint4 bl4 = WlF[kb * 256 + ct * 64 + lane];
                bf16x8 bh = *reinterpret_cast<bf16x8*>(&bh4);
                bf16x8 bl = *reinterpret_cast<bf16x8*>(&bl4);
                acc[ct] = __builtin_amdgcn_mfma_f32_16x16x32_bf16(ah, bh, acc[ct], 0, 0, 0);
                acc[ct] = __builtin_amdgcn_mfma_f32_16x16x32_bf16(ah, bl, acc[ct], 0, 0, 0);
                acc[ct] = __builtin_amdgcn_mfma_f32_16x16x32_bf16(al, bh, acc[ct], 0, 0, 0);
            }
        }
    };

    phaseA(0);

    for (int t = 0; t < T_STEPS; t++){
        if (t > 0){
            if (w == 0){
                const unsigned need = 32u * (unsigned)((t + 1) >> 1);
                while (__hip_atomic_load(&cnt[t & 1], __ATOMIC_RELAXED, __HIP_MEMORY_SCOPE_AGENT) < need)
                    __builtin_amdgcn_s_sleep(1);
            }
            __syncthreads();
        }

        const u64t* hp = reinterpret_cast<const u64t*>(hbuf)
                       + (size_t)(t & 1) * 8192 + (size_t)row * 256;
        u64t hv[16];
        #pragma unroll
        for (int i = 0; i < 4; i++){
            int base = (kq * 4 + i) * 16 + kgrp * 4;
            #pragma unroll
            for (int jp = 0; jp < 4; jp++)
                hv[i * 4 + jp] = __hip_atomic_load(hp + base + jp,
                                                   __ATOMIC_RELAXED, __HIP_MEMORY_SCOPE_AGENT);
        }

        #pragma unroll
        for (int i = 0; i < 4; i++){
            int kb = kq * 4 + i;
            bf16x8 ah, al;
            #pragma unroll
            for (int jp = 0; jp < 4; jp++){
                u64t q = hv[i * 4 + jp];
                unsigned a = (unsigned)q;
                unsigned b = (unsigned)(q >> 32);
                ah[jp * 2    ] = (short)(a & 0xffffu); al[jp * 2    ] = (short)(a >> 16);
                ah[jp * 2 + 1] = (short)(b & 0xffffu); al[jp * 2 + 1] = (short)(b >> 16);
            }
            #pragma unroll
            for (int ct = 0; ct < 4; ct++){
                uint4 uh4 = UhF[kb * 256 + ct * 64 + lane];
                uint4 ul4 = UlF[kb * 256 + ct * 64 + lane];
                bf16x8 uh = *reinterpret_cast<bf16x8*>(&uh4);
                bf16x8 ul = *reinterpret_cast<bf16x8*>(&ul4);
                acc[ct] = __builtin_amdgcn_mfma_f32_16x16x32_bf16(ah, uh, acc[ct], 0, 0, 0);
                acc[ct] = __builtin_amdgcn_mfma_f32_16x16x32_bf16(ah, ul, acc[ct], 0, 0, 0);
                acc[ct] = __builtin_amdgcn_mfma_f32_16x16x32_bf16(al, uh, acc[ct], 0, 0, 0);
            }
        }

        #pragma unroll
        for (int ct = 0; ct < 4; ct++)
            #pragma unroll
            for (int r = 0; r < 4; r++)
                z_lds[kq][bt * 16 + kgrp * 4 + r][ct * 16 + lc] = acc[ct][r];
        __syncthreads();

        {
            float z[4];
            #pragma unroll
            for (int g = 0; g < 4; g++)
                z[g] = z_lds[0][cb][g * 16 + chc] + z_lds[1][cb][g * 16 + chc]
                     + z_lds[2][cb][g * 16 + chc] + z_lds[3][cb][g * 16 + chc] + bias_g[g];
            float ig = 1.f / (1.f + __expf(-z[0]));
            float fg = 1.f / (1.f + __expf(-z[1]));
            float gg = tanhf(z[2]);
            float og = 1.f / (1.f + __expf(-z[3]));
            float cn = fg * c_state + ig * gg;
            c_state = cn;
            float hn = og * tanhf(cn);
            out[16384 + ((size_t)t * BATCH + cb) * HDIM + col] = hn;
            if (t == T_STEPS - 1){
                out[(size_t)cb * HDIM + col] = hn;
                out[16384 + (size_t)T_STEPS * BATCH * HDIM + (size_t)cb * HDIM + col] = hn;
            }
            unsigned short hi = f2bf(hn);
            unsigned short lo = f2bf(hn - bf2f(hi));
            __hip_atomic_store(&hbuf[(size_t)((t + 1) & 1) * (BATCH * HDIM) + (size_t)cb * HDIM + col],
                               (unsigned)hi | ((unsigned)lo << 16),
                               __ATOMIC_RELAXED, __HIP_MEMORY_SCOPE_AGENT);
        }
        __syncthreads();
        if (tid == 0)
            __hip_atomic_fetch_add(&cnt[(t + 1) & 1], 1u,
                                   __ATOMIC_RELAXED, __HIP_MEMORY_SCOPE_AGENT);

        #pragma unroll
        for (int ct = 0; ct < 4; ct++)
            #pragma unroll
            for (int r = 0; r < 4; r++) acc[ct][r] = 0.f;
        if (t + 1 < T_STEPS) phaseA(t + 1);
    }
}

// ============================ LAUNCH =======================================
extern "C" void kernel_launch(void* const* d_in, const int* in_sizes, int n_in,
                              void* d_out, int out_size, void* d_ws, size_t ws_size,
                              hipStream_t stream){
    const float* src = (const float*)d_in[0];
    const float* W   = (const float*)d_in[1];
    const float* U   = (const float*)d_in[2];
    const float* b   = (const float*)d_in[3];
    const float* h0  = (const float*)d_in[4];
    const float* c0  = (const float*)d_in[5];
    float* out = (float*)d_out;
    char* ws = (char*)d_ws;

    int TCH = 0;
    const int cand[5] = {256, 128, 64, 32, 16};
    for (int i = 0; i < 5; i++){
        if (FIXED_WS + (size_t)cand[i] * 262144ull <= ws_size){ TCH = cand[i]; break; }
    }

    if (TCH > 0){
        unsigned*       hbuf = (unsigned*)(ws);
        unsigned*       done = (unsigned*)(ws + 0x020000ull);
        float*          c_ws = (float*)(ws + 0x021000ull);
        unsigned short* Wh   = (unsigned short*)(ws + 0x031000ull);
        unsigned short* Wl   = (unsigned short*)(ws + 0x231000ull);
        unsigned short* Uh   = (unsigned short*)(ws + 0x431000ull);
        unsigned short* Ul   = (unsigned short*)(ws + 0x631000ull);
        float*          xWc  = (float*)(ws + FIXED_WS);

        hipMemsetAsync(done, 0, 128, stream);
        prep_kernel<<<1024, 256, 0, stream>>>(W, U, h0, Wh, Wl, Uh, Ul, hbuf);
        const int nch = T_STEPS / TCH;
        for (int i = 0; i < nch; i++){
            int t0 = i * TCH;
            xw_gemm_chunk<<<(TCH / 4) * 32, 256, 0, stream>>>(src, Wh, Wl, xWc, t0);
            lstm_scan_fast<<<32, 512, 0, stream>>>(b, c0, Uh, Ul, hbuf, done,
                                                   xWc, c_ws, out, t0, TCH);
        }
    } else {
        unsigned*       hbuf = (unsigned*)(ws);
        unsigned*       cnt  = (unsigned*)(ws + 0x20000);
        unsigned short* Wh   = (unsigned short*)(ws + 0x21000);
        unsigned short* Wl   = Wh + 1048576;
        unsigned short* Uh   = Wl + 1048576;
        unsigned short* Ul   = Uh + 1048576;
        hipMemsetAsync(cnt, 0, 8, stream);
        prep_kernel<<<1024, 256, 0, stream>>>(W, U, h0, Wh, Wl, Uh, Ul, hbuf);
        lstm_scan_r7<<<32, 512, 0, stream>>>(src, b, c0, Wh, Wl, Uh, Ul, hbuf, cnt, out);
    }
}